// Round 1
// baseline (363.144 us; speedup 1.0000x reference)
//
#include <hip/hip_runtime.h>
#include <hip/hip_bf16.h>
#include <math.h>

// Problem constants
#define BB   2048
#define INH  512
#define HH   512
#define KK   32
#define OUTD 512
#define KDIM 1536   // IN + 2H (padded K for all 4 gates)
#define NG   2048   // 4 * H

typedef __attribute__((ext_vector_type(8))) short short8;
typedef __attribute__((ext_vector_type(4))) float floatx4;

__device__ __forceinline__ void async_copy16(void* lds, const void* g) {
  __builtin_amdgcn_global_load_lds(
      (const __attribute__((address_space(1))) unsigned int*)g,
      (__attribute__((address_space(3))) unsigned int*)lds,
      16, 0, 0);
}

__device__ __forceinline__ float sigmoidf_(float x) {
  return 1.0f / (1.0f + __expf(-x));
}

__device__ __forceinline__ unsigned short to_bf16(float f) {
  __hip_bfloat16 h = __float2bfloat16(f);
  return *reinterpret_cast<unsigned short*>(&h);
}

// ---------------------------------------------------------------------------
// K1: pack A (sample|hidden|d0) -> bf16 [2048][1536],
//     pack W (Wf ; Wi|0 ; Wo|0 ; Wc|0) -> bf16 [2048][1536],
//     pack Wout -> bf16 [512][512]
// ---------------------------------------------------------------------------
__global__ __launch_bounds__(256) void pack_kernel(
    const float* __restrict__ sample, const float* __restrict__ hidden,
    const float* __restrict__ d0,
    const float* __restrict__ Wc, const float* __restrict__ Wi,
    const float* __restrict__ Wf, const float* __restrict__ Wo,
    const float* __restrict__ Wout,
    unsigned short* __restrict__ Abf, unsigned short* __restrict__ Wbf,
    unsigned short* __restrict__ Woutbf)
{
  const int NA = BB * KDIM;
  int i = blockIdx.x * 256 + threadIdx.x;
  if (i < NA) {
    int r = i / KDIM, c = i - r * KDIM;
    float v = (c < 512) ? sample[r * 512 + c]
            : (c < 1024) ? hidden[r * 512 + (c - 512)]
                         : d0[r * 512 + (c - 1024)];
    Abf[i] = to_bf16(v);
  } else if (i < 2 * NA) {
    int j = i - NA;
    int g = j / KDIM, c = j - g * KDIM;
    int q = g >> 9, h = g & 511;
    float v;
    if (q == 0)           v = Wf[(size_t)h * 1536 + c];
    else if (c >= 1024)   v = 0.0f;
    else if (q == 1)      v = Wi[(size_t)h * 1024 + c];
    else if (q == 2)      v = Wo[(size_t)h * 1024 + c];
    else                  v = Wc[(size_t)h * 1024 + c];
    Wbf[j] = to_bf16(v);
  } else {
    int j = i - 2 * NA;   // j < 512*512 guaranteed by grid sizing
    Woutbf[j] = to_bf16(Wout[j]);
  }
}

// ---------------------------------------------------------------------------
// K2/K4: bf16 MFMA GEMM  C[M][N] = A[M][K] @ Bw[N][K]^T  (+ fused epilogue)
// MODE 0: gates — col gate = col>>9 in {f,i,o,c}; writes d_values,i,o,c~
// MODE 1: output — +bout, plain store
// 128x128 tile, BK=32, 256 threads = 4 waves, each wave 64x64.
// ---------------------------------------------------------------------------
template<int MODE>
__global__ __launch_bounds__(256) void gemm_bf16(
    const unsigned short* __restrict__ A,
    const unsigned short* __restrict__ Bw,
    int M, int N, int K,
    const float* __restrict__ bias0, const float* __restrict__ bias1,
    const float* __restrict__ bias2, const float* __restrict__ bias3,
    float* __restrict__ o0, float* __restrict__ o1,
    float* __restrict__ o2, float* __restrict__ o3)
{
  __shared__ __align__(16) unsigned short As[128 * 32];
  __shared__ __align__(16) unsigned short Bs[128 * 32];
  const int tid  = threadIdx.x;
  const int lane = tid & 63;
  const int wid  = tid >> 6;
  const int wr   = wid >> 1, wc = wid & 1;
  const int tm   = blockIdx.y * 128, tn = blockIdx.x * 128;

  floatx4 acc[4][4];
  #pragma unroll
  for (int mi = 0; mi < 4; ++mi)
    #pragma unroll
    for (int ni = 0; ni < 4; ++ni)
      acc[mi][ni] = (floatx4){0.f, 0.f, 0.f, 0.f};

  for (int k0 = 0; k0 < K; k0 += 32) {
    // stage 128x32 A-tile and B-tile: 512 chunks of 16B each, 2 per thread
    #pragma unroll
    for (int p = 0; p < 2; ++p) {
      int c   = tid + p * 256;
      int row = c >> 2;
      int kg  = (c & 3) << 3;
      async_copy16(&As[c * 8], &A[(size_t)(tm + row) * K + k0 + kg]);
      async_copy16(&Bs[c * 8], &Bw[(size_t)(tn + row) * K + k0 + kg]);
    }
    asm volatile("s_waitcnt vmcnt(0)" ::: "memory");
    __syncthreads();

    short8 af[4], bf8[4];
    const int kb  = (lane >> 4) << 3;
    const int r16 = lane & 15;
    #pragma unroll
    for (int mi = 0; mi < 4; ++mi)
      af[mi] = *(const short8*)&As[(wr * 64 + mi * 16 + r16) * 32 + kb];
    #pragma unroll
    for (int ni = 0; ni < 4; ++ni)
      bf8[ni] = *(const short8*)&Bs[(wc * 64 + ni * 16 + r16) * 32 + kb];

    #pragma unroll
    for (int mi = 0; mi < 4; ++mi)
      #pragma unroll
      for (int ni = 0; ni < 4; ++ni)
        acc[mi][ni] = __builtin_amdgcn_mfma_f32_16x16x32_bf16(
            af[mi], bf8[ni], acc[mi][ni], 0, 0, 0);
    __syncthreads();
  }

  // epilogue: C/D layout col=lane&15, row=(lane>>4)*4+r
  #pragma unroll
  for (int mi = 0; mi < 4; ++mi) {
    const int row0 = tm + wr * 64 + mi * 16 + (lane >> 4) * 4;
    #pragma unroll
    for (int ni = 0; ni < 4; ++ni) {
      const int col = tn + wc * 64 + ni * 16 + (lane & 15);
      floatx4 v = acc[mi][ni];
      if (MODE == 0) {
        const int gate = col >> 9;
        const int h    = col & 511;
        #pragma unroll
        for (int r = 0; r < 4; ++r) {
          const int row = row0 + r;
          float x = v[r];
          if (gate == 0)      o0[(size_t)row * 512 + h] = 0.5f * sigmoidf_(x + bias0[h]);
          else if (gate == 1) o1[(size_t)row * 512 + h] = sigmoidf_(x + bias1[h]);
          else if (gate == 2) o2[(size_t)row * 512 + h] = sigmoidf_(x + bias2[h]);
          else                o3[(size_t)row * 512 + h] = tanhf(x + bias3[h]);
        }
      } else {
        #pragma unroll
        for (int r = 0; r < 4; ++r) {
          const int row = row0 + r;
          o0[(size_t)row * N + col] = v[r] + bias0[col];
        }
      }
    }
  }
}

// ---------------------------------------------------------------------------
// K3: fused fractional cell update + shifted h_c_1 copy + hidden_new
// one thread = 4 consecutive h (float4)
// ---------------------------------------------------------------------------
__global__ __launch_bounds__(256) void cell_kernel(
    const float4* __restrict__ ct,     // [32][NBH4]
    const float4* __restrict__ dv,     // d_values
    const float4* __restrict__ ig,
    const float4* __restrict__ og,
    const float4* __restrict__ cg,     // c_tilde
    float4* __restrict__ hc1,          // [32][NBH4]
    float4* __restrict__ hnew,
    ushort4* __restrict__ hbf)         // bf16 copy of hidden_new
{
  const int NBH4 = (BB * HH) / 4;      // 262144
  const int idx  = blockIdx.x * 256 + threadIdx.x;

  float4 d = dv[idx];
  float px = 1.f, py = 1.f, pz = 1.f, pw = 1.f;
  float fx = 0.f, fy = 0.f, fz = 0.f, fw = 0.f;

  #pragma unroll
  for (int i = 0; i < 32; ++i) {
    const int j = 31 - i;
    float4 c = ct[(size_t)j * NBH4 + idx];
    const float inv = 1.0f / (float)(i + 1);
    const float fi  = (float)i;
    px *= (fi - d.x) * inv;  py *= (fi - d.y) * inv;
    pz *= (fi - d.z) * inv;  pw *= (fi - d.w) * inv;
    fx -= c.x * px;  fy -= c.y * py;
    fz -= c.z * pz;  fw -= c.w * pw;
    if (j >= 1) hc1[(size_t)(j - 1) * NBH4 + idx] = c;   // exact fp32 copy
  }

  float4 iv = ig[idx], ov = og[idx], cv = cg[idx];
  float4 cell;
  cell.x = fx + cv.x * iv.x;  cell.y = fy + cv.y * iv.y;
  cell.z = fz + cv.z * iv.z;  cell.w = fw + cv.w * iv.w;
  hc1[(size_t)31 * NBH4 + idx] = cell;

  float4 hn;
  hn.x = tanhf(cell.x) * ov.x;  hn.y = tanhf(cell.y) * ov.y;
  hn.z = tanhf(cell.z) * ov.z;  hn.w = tanhf(cell.w) * ov.w;
  hnew[idx] = hn;

  ushort4 hb;
  hb.x = to_bf16(hn.x);  hb.y = to_bf16(hn.y);
  hb.z = to_bf16(hn.z);  hb.w = to_bf16(hn.w);
  hbf[idx] = hb;
}

// ---------------------------------------------------------------------------
extern "C" void kernel_launch(void* const* d_in, const int* in_sizes, int n_in,
                              void* d_out, int out_size, void* d_ws, size_t ws_size,
                              hipStream_t stream) {
  const float* sample = (const float*)d_in[0];
  const float* hidden = (const float*)d_in[1];
  const float* cell_t = (const float*)d_in[2];
  const float* d0     = (const float*)d_in[3];
  const float* Wc     = (const float*)d_in[4];
  const float* bc     = (const float*)d_in[5];
  const float* Wi     = (const float*)d_in[6];
  const float* bi     = (const float*)d_in[7];
  const float* Wf     = (const float*)d_in[8];
  const float* bf     = (const float*)d_in[9];
  const float* Wo     = (const float*)d_in[10];
  const float* bo     = (const float*)d_in[11];
  const float* Wout   = (const float*)d_in[12];
  const float* bout   = (const float*)d_in[13];

  float* out        = (float*)d_out;                       // [2048][512]
  float* out_hidden = out + (size_t)BB * OUTD;             // [2048][512]
  float* out_hc1    = out_hidden + (size_t)BB * HH;        // [32][2048][512]
  float* out_dv     = out_hc1 + (size_t)KK * BB * HH;      // [2048][512]

  char* ws = (char*)d_ws;
  unsigned short* Abf    = (unsigned short*)ws;                    // 2048*1536
  unsigned short* Wbf    = Abf + (size_t)BB * KDIM;                // 2048*1536
  unsigned short* Woutbf = Wbf + (size_t)NG * KDIM;                // 512*512
  float* ig  = (float*)(Woutbf + (size_t)OUTD * HH);
  float* og  = ig + (size_t)BB * HH;
  float* cg  = og + (size_t)BB * HH;
  unsigned short* hbf = (unsigned short*)(cg + (size_t)BB * HH);   // 2048*512

  // K1: pack bf16 operands
  pack_kernel<<<25600, 256, 0, stream>>>(sample, hidden, d0, Wc, Wi, Wf, Wo,
                                         Wout, Abf, Wbf, Woutbf);
  // K2: fused 4-gate GEMM + activations
  gemm_bf16<0><<<dim3(16, 16), 256, 0, stream>>>(
      Abf, Wbf, BB, NG, KDIM, bf, bi, bo, bc, out_dv, ig, og, cg);
  // K3: fractional cell + h_c_1 shift + hidden_new
  cell_kernel<<<1024, 256, 0, stream>>>(
      (const float4*)cell_t, (const float4*)out_dv, (const float4*)ig,
      (const float4*)og, (const float4*)cg, (float4*)out_hc1,
      (float4*)out_hidden, (ushort4*)hbf);
  // K4: output GEMM
  gemm_bf16<1><<<dim3(4, 16), 256, 0, stream>>>(
      hbf, Woutbf, BB, OUTD, HH, bout, nullptr, nullptr, nullptr,
      out, nullptr, nullptr, nullptr);
}

// Round 3
// 332.421 us; speedup vs baseline: 1.0924x; 1.0924x over previous
//
#include <hip/hip_runtime.h>
#include <hip/hip_bf16.h>
#include <math.h>

// Problem constants
#define BB   2048
#define HH   512
#define KK   32
#define OUTD 512
#define KDIM 1536   // IN + 2H (padded K for all 4 gates)
#define NG   2048   // 4 * H

typedef __attribute__((ext_vector_type(8))) short short8;
typedef __attribute__((ext_vector_type(4))) float floatx4;

__device__ __forceinline__ void async_copy16(void* lds, const void* g) {
  __builtin_amdgcn_global_load_lds(
      (const __attribute__((address_space(1))) unsigned int*)g,
      (__attribute__((address_space(3))) unsigned int*)lds,
      16, 0, 0);
}

__device__ __forceinline__ float sigmoidf_(float x) {
  return 1.0f / (1.0f + __expf(-x));
}

__device__ __forceinline__ unsigned short to_bf16(float f) {
  __hip_bfloat16 h = __float2bfloat16(f);
  return *reinterpret_cast<unsigned short*>(&h);
}

// ---------------------------------------------------------------------------
// Pre-swizzled packed layout (shared by pack, cell-hbf-write, and gemm reads):
// element (r, k) of an [R][K] bf16 matrix lives at
//   r*K + (k & ~63) + ( ((k>>3)&7) ^ (r&7) )*8 + (k&7)
// i.e. within each 64-elem K-window, 8-elem chunks are XOR-permuted by row&7.
// The GEMM stages 64-elem windows LINEARLY into LDS (global_load_lds needs a
// linear dest — rule #21), and applies the same XOR on the ds_read side.
// Result: lanes 0..15 (rows r..r+15, same logical chunk) hit 8 distinct
// 16B bank slots -> bank-conflict-free ds_read_b128 (T2).
// NOTE (R2 fix): destination chunk = (qq & ~7) | ((qq&7)^(r&7)).  The R1
// draft used (qq & 0x38), which aliases all windows >= 1 into window 0.
// ---------------------------------------------------------------------------

// ---------------------------------------------------------------------------
// K1: pack A=[sample|hidden|d0] -> bf16 [2048][1536] (swizzled),
//     W=[Wf ; Wi|0 ; Wo|0 ; Wc|0] -> bf16 [2048][1536] (swizzled),
//     Wout -> bf16 [512][512] (swizzled).
// grid: 4608 row-blocks x 192 threads; 1 thread = one 8-elem chunk (16B store)
// ---------------------------------------------------------------------------
__global__ __launch_bounds__(192) void pack_kernel(
    const float* __restrict__ sample, const float* __restrict__ hidden,
    const float* __restrict__ d0,
    const float* __restrict__ Wc, const float* __restrict__ Wi,
    const float* __restrict__ Wf, const float* __restrict__ Wo,
    const float* __restrict__ Wout,
    unsigned short* __restrict__ Abf, unsigned short* __restrict__ Wbf,
    unsigned short* __restrict__ Woutbf)
{
  const int r  = blockIdx.x;
  const int qq = threadIdx.x;          // chunk index within row
  float4 v0, v1;

  if (r < 2048) {                      // ---- A row r, K=1536
    const int k0 = qq * 8;
    const float* src = (k0 < 512)  ? sample + (size_t)r * 512 + k0
                     : (k0 < 1024) ? hidden + (size_t)r * 512 + (k0 - 512)
                                   : d0     + (size_t)r * 512 + (k0 - 1024);
    v0 = ((const float4*)src)[0];
    v1 = ((const float4*)src)[1];
    const int dc = (qq & ~7) | ((qq & 7) ^ (r & 7));
    short8 o;
    o[0]=to_bf16(v0.x); o[1]=to_bf16(v0.y); o[2]=to_bf16(v0.z); o[3]=to_bf16(v0.w);
    o[4]=to_bf16(v1.x); o[5]=to_bf16(v1.y); o[6]=to_bf16(v1.z); o[7]=to_bf16(v1.w);
    *(short8*)&Abf[(size_t)r * KDIM + dc * 8] = o;
  } else if (r < 4096) {               // ---- W row g, K=1536
    const int g = r - 2048;
    const int q4 = g >> 9, h = g & 511;
    const int k0 = qq * 8;
    if (q4 == 0) {
      const float* s = Wf + (size_t)h * 1536 + k0;
      v0 = ((const float4*)s)[0]; v1 = ((const float4*)s)[1];
    } else if (k0 >= 1024) {
      v0 = make_float4(0.f,0.f,0.f,0.f); v1 = v0;
    } else {
      const float* s = (q4 == 1 ? Wi : q4 == 2 ? Wo : Wc) + (size_t)h * 1024 + k0;
      v0 = ((const float4*)s)[0]; v1 = ((const float4*)s)[1];
    }
    const int dc = (qq & ~7) | ((qq & 7) ^ (g & 7));
    short8 o;
    o[0]=to_bf16(v0.x); o[1]=to_bf16(v0.y); o[2]=to_bf16(v0.z); o[3]=to_bf16(v0.w);
    o[4]=to_bf16(v1.x); o[5]=to_bf16(v1.y); o[6]=to_bf16(v1.z); o[7]=to_bf16(v1.w);
    *(short8*)&Wbf[(size_t)g * KDIM + dc * 8] = o;
  } else {                             // ---- Wout row rw, K=512
    const int rw = r - 4096;
    if (qq < 64) {
      const int k0 = qq * 8;
      const float* s = Wout + (size_t)rw * 512 + k0;
      v0 = ((const float4*)s)[0]; v1 = ((const float4*)s)[1];
      const int dc = (qq & ~7) | ((qq & 7) ^ (rw & 7));
      short8 o;
      o[0]=to_bf16(v0.x); o[1]=to_bf16(v0.y); o[2]=to_bf16(v0.z); o[3]=to_bf16(v0.w);
      o[4]=to_bf16(v1.x); o[5]=to_bf16(v1.y); o[6]=to_bf16(v1.z); o[7]=to_bf16(v1.w);
      *(short8*)&Woutbf[(size_t)rw * 512 + dc * 8] = o;
    }
  }
}

// ---------------------------------------------------------------------------
// K2/K4: bf16 MFMA GEMM  C[M][N] = A[M][K] @ Bw[N][K]^T  (+ fused epilogue)
// BK=64, double-buffered LDS, 2-phase pipeline with counted vmcnt (T3/T4),
// XOR-swizzled ds_read (T2, pre-swizzled global). 256 thr = 4 waves (2x2),
// each wave (BM/2)x(BN/2).
// MODE 0: 4-gate epilogue (gate uniform per block since BN=128 | 512-aligned)
// MODE 1: + bias, plain store
// ---------------------------------------------------------------------------
template<int BM, int BN, int MODE>
__global__ __launch_bounds__(256) void gemm2(
    const unsigned short* __restrict__ A,
    const unsigned short* __restrict__ Bw,
    int K, int NT, int N,
    const float* __restrict__ bias0, const float* __restrict__ bias1,
    const float* __restrict__ bias2, const float* __restrict__ bias3,
    float* __restrict__ o0, float* __restrict__ o1,
    float* __restrict__ o2, float* __restrict__ o3)
{
  constexpr int MI = BM / 32, NI = BN / 32;      // 16x16 frags per wave dim
  __shared__ __align__(16) unsigned short As[2][BM * 64];
  __shared__ __align__(16) unsigned short Bs[2][BN * 64];
  const int tid  = threadIdx.x;
  const int lane = tid & 63;
  const int wid  = tid >> 6;
  const int wr   = wid >> 1, wc = wid & 1;
  const int tm   = blockIdx.y * BM, tn = blockIdx.x * BN;

  floatx4 acc[MI][NI];
  #pragma unroll
  for (int mi = 0; mi < MI; ++mi)
    #pragma unroll
    for (int ni = 0; ni < NI; ++ni)
      acc[mi][ni] = (floatx4){0.f, 0.f, 0.f, 0.f};

  const char* Abase = (const char*)A;
  const char* Bbase = (const char*)Bw;
  const size_t rowbytes = (size_t)K * 2;

  auto stage = [&](int buf, int t) {
    #pragma unroll
    for (int p = 0; p < BM * 8 / 256; ++p) {
      const int c = tid + p * 256;
      const int row = c >> 3, ci = c & 7;
      async_copy16(&As[buf][c * 8],
                   Abase + (size_t)(tm + row) * rowbytes + (size_t)t * 128 + ci * 16);
    }
    #pragma unroll
    for (int p = 0; p < BN * 8 / 256; ++p) {
      const int c = tid + p * 256;
      const int row = c >> 3, ci = c & 7;
      async_copy16(&Bs[buf][c * 8],
                   Bbase + (size_t)(tn + row) * rowbytes + (size_t)t * 128 + ci * 16);
    }
  };

  stage(0, 0);
  const int r16 = lane & 15, kq = lane >> 4;

  for (int t = 0; t < NT; ++t) {
    const int cur = t & 1;
    if (t + 1 < NT) {
      stage(cur ^ 1, t + 1);      // issue next tile BEFORE computing current
      if constexpr (BM + BN == 256)
        asm volatile("s_waitcnt vmcnt(8)" ::: "memory");   // wait tile t only
      else
        asm volatile("s_waitcnt vmcnt(4)" ::: "memory");
    } else {
      asm volatile("s_waitcnt vmcnt(0)" ::: "memory");
    }
    __syncthreads();

    #pragma unroll
    for (int ks = 0; ks < 2; ++ks) {
      short8 af[MI], bfr[NI];
      #pragma unroll
      for (int mi = 0; mi < MI; ++mi) {
        const int r  = wr * (BM / 2) + mi * 16 + r16;
        const int pc = (ks * 4 + kq) ^ (r & 7);
        af[mi] = *(const short8*)&As[cur][r * 64 + pc * 8];
      }
      #pragma unroll
      for (int ni = 0; ni < NI; ++ni) {
        const int r  = wc * (BN / 2) + ni * 16 + r16;
        const int pc = (ks * 4 + kq) ^ (r & 7);
        bfr[ni] = *(const short8*)&Bs[cur][r * 64 + pc * 8];
      }
      #pragma unroll
      for (int mi = 0; mi < MI; ++mi)
        #pragma unroll
        for (int ni = 0; ni < NI; ++ni)
          acc[mi][ni] = __builtin_amdgcn_mfma_f32_16x16x32_bf16(
              af[mi], bfr[ni], acc[mi][ni], 0, 0, 0);
    }
    __syncthreads();
  }

  // epilogue: C/D layout col=lane&15, row=(lane>>4)*4+r
  if (MODE == 0) {
    // BN=128 tile lies inside one 512-wide gate -> gate is block-uniform
    const int gate = tn >> 9;
    float* og   = (gate == 0) ? o0 : (gate == 1) ? o1 : (gate == 2) ? o2 : o3;
    const float* bg = (gate == 0) ? bias0 : (gate == 1) ? bias1
                    : (gate == 2) ? bias2 : bias3;
    #pragma unroll
    for (int mi = 0; mi < MI; ++mi) {
      const int row0 = tm + wr * (BM / 2) + mi * 16 + (lane >> 4) * 4;
      #pragma unroll
      for (int ni = 0; ni < NI; ++ni) {
        const int col = tn + wc * (BN / 2) + ni * 16 + (lane & 15);
        const int h   = col & 511;
        const float b = bg[h];
        floatx4 v = acc[mi][ni];
        #pragma unroll
        for (int r = 0; r < 4; ++r) {
          const float x = v[r] + b;
          float res;
          if (gate == 0)      res = 0.5f * sigmoidf_(x);
          else if (gate == 3) res = tanhf(x);
          else                res = sigmoidf_(x);
          og[(size_t)(row0 + r) * 512 + h] = res;
        }
      }
    }
  } else {
    #pragma unroll
    for (int mi = 0; mi < MI; ++mi) {
      const int row0 = tm + wr * (BM / 2) + mi * 16 + (lane >> 4) * 4;
      #pragma unroll
      for (int ni = 0; ni < NI; ++ni) {
        const int col = tn + wc * (BN / 2) + ni * 16 + (lane & 15);
        floatx4 v = acc[mi][ni];
        #pragma unroll
        for (int r = 0; r < 4; ++r)
          o0[(size_t)(row0 + r) * N + col] = v[r] + bias0[col];
      }
    }
  }
}

// ---------------------------------------------------------------------------
// K3: fused fractional cell update + shifted h_c_1 copy + hidden_new
// one thread = 4 consecutive h (float4); planes processed in 4-deep groups
// so ~4 independent 16B loads are in flight without register blowup.
// ---------------------------------------------------------------------------
__global__ __launch_bounds__(256) void cell_kernel(
    const float4* __restrict__ ct,     // [32][NBH4]
    const float4* __restrict__ dv,     // d_values
    const float4* __restrict__ ig,
    const float4* __restrict__ og,
    const float4* __restrict__ cg,     // c_tilde
    float4* __restrict__ hc1,          // [32][NBH4]
    float4* __restrict__ hnew,
    unsigned short* __restrict__ hbf)  // bf16 copy of hidden_new (swizzled)
{
  const int NBH4 = (BB * HH) / 4;      // 262144
  const int idx  = blockIdx.x * 256 + threadIdx.x;

  const float4 d = dv[idx];
  float px = 1.f, py = 1.f, pz = 1.f, pw = 1.f;
  float fx = 0.f, fy = 0.f, fz = 0.f, fw = 0.f;

  #pragma unroll
  for (int g = 7; g >= 0; --g) {       // planes j = 4g+3 .. 4g (descending)
    float4 c3 = ct[(size_t)(4 * g + 3) * NBH4 + idx];
    float4 c2 = ct[(size_t)(4 * g + 2) * NBH4 + idx];
    float4 c1 = ct[(size_t)(4 * g + 1) * NBH4 + idx];
    float4 c0 = ct[(size_t)(4 * g + 0) * NBH4 + idx];
    #pragma unroll
    for (int s = 3; s >= 0; --s) {
      const int j = 4 * g + s;
      const int i = 31 - j;
      const float inv = 1.0f / (float)(i + 1);
      const float fi  = (float)i;
      const float4 c = (s == 3) ? c3 : (s == 2) ? c2 : (s == 1) ? c1 : c0;
      px *= (fi - d.x) * inv;  py *= (fi - d.y) * inv;
      pz *= (fi - d.z) * inv;  pw *= (fi - d.w) * inv;
      fx -= c.x * px;  fy -= c.y * py;
      fz -= c.z * pz;  fw -= c.w * pw;
      if (j >= 1) hc1[(size_t)(j - 1) * NBH4 + idx] = c;   // exact fp32 copy
    }
  }

  const float4 iv = ig[idx], ov = og[idx], cv = cg[idx];
  float4 cell;
  cell.x = fx + cv.x * iv.x;  cell.y = fy + cv.y * iv.y;
  cell.z = fz + cv.z * iv.z;  cell.w = fw + cv.w * iv.w;
  hc1[(size_t)31 * NBH4 + idx] = cell;

  float4 hn;
  hn.x = tanhf(cell.x) * ov.x;  hn.y = tanhf(cell.y) * ov.y;
  hn.z = tanhf(cell.z) * ov.z;  hn.w = tanhf(cell.w) * ov.w;
  hnew[idx] = hn;

  // swizzled bf16 write for gemm<1>'s A operand
  const int b  = idx >> 7;
  const int h0 = (idx & 127) * 4;
  const int qc = h0 >> 3;
  const int dc = (qc & ~7) | ((qc & 7) ^ (b & 7));
  ushort4 hb;
  hb.x = to_bf16(hn.x);  hb.y = to_bf16(hn.y);
  hb.z = to_bf16(hn.z);  hb.w = to_bf16(hn.w);
  *(ushort4*)&hbf[(size_t)b * 512 + dc * 8 + (h0 & 7)] = hb;
}

// ---------------------------------------------------------------------------
extern "C" void kernel_launch(void* const* d_in, const int* in_sizes, int n_in,
                              void* d_out, int out_size, void* d_ws, size_t ws_size,
                              hipStream_t stream) {
  const float* sample = (const float*)d_in[0];
  const float* hidden = (const float*)d_in[1];
  const float* cell_t = (const float*)d_in[2];
  const float* d0     = (const float*)d_in[3];
  const float* Wc     = (const float*)d_in[4];
  const float* bc     = (const float*)d_in[5];
  const float* Wi     = (const float*)d_in[6];
  const float* bi     = (const float*)d_in[7];
  const float* Wf     = (const float*)d_in[8];
  const float* bf     = (const float*)d_in[9];
  const float* Wo     = (const float*)d_in[10];
  const float* bo     = (const float*)d_in[11];
  const float* Wout   = (const float*)d_in[12];
  const float* bout   = (const float*)d_in[13];

  float* out        = (float*)d_out;                       // [2048][512]
  float* out_hidden = out + (size_t)BB * OUTD;             // [2048][512]
  float* out_hc1    = out_hidden + (size_t)BB * HH;        // [32][2048][512]
  float* out_dv     = out_hc1 + (size_t)KK * BB * HH;      // [2048][512]

  char* ws = (char*)d_ws;
  unsigned short* Abf    = (unsigned short*)ws;                    // 2048*1536
  unsigned short* Wbf    = Abf + (size_t)BB * KDIM;                // 2048*1536
  unsigned short* Woutbf = Wbf + (size_t)NG * KDIM;                // 512*512
  float* ig  = (float*)(Woutbf + (size_t)OUTD * HH);
  float* og  = ig + (size_t)BB * HH;
  float* cg  = og + (size_t)BB * HH;
  unsigned short* hbf = (unsigned short*)(cg + (size_t)BB * HH);   // 2048*512

  // K1: pack bf16 operands (pre-swizzled layout)
  pack_kernel<<<4608, 192, 0, stream>>>(sample, hidden, d0, Wc, Wi, Wf, Wo,
                                        Wout, Abf, Wbf, Woutbf);
  // K2: fused 4-gate GEMM + activations (M=2048, N=2048, K=1536)
  gemm2<128, 128, 0><<<dim3(16, 16), 256, 0, stream>>>(
      Abf, Wbf, KDIM, KDIM / 64, NG, bf, bi, bo, bc, out_dv, ig, og, cg);
  // K3: fractional cell + h_c_1 shift + hidden_new
  cell_kernel<<<1024, 256, 0, stream>>>(
      (const float4*)cell_t, (const float4*)out_dv, (const float4*)ig,
      (const float4*)og, (const float4*)cg, (float4*)out_hc1,
      (float4*)out_hidden, hbf);
  // K4: output GEMM (M=2048, N=512, K=512), 64x64 tiles -> 256 blocks
  gemm2<64, 64, 1><<<dim3(8, 32), 256, 0, stream>>>(
      hbf, Woutbf, HH, HH / 64, OUTD, bout, nullptr, nullptr, nullptr,
      out, nullptr, nullptr, nullptr);
}